// Round 13
// baseline (30.381 us; speedup 1.0000x reference)
//
#include <hip/hip_runtime.h>
#include <hip/hip_fp16.h>
#include <math.h>

// T=24, NSEQ=16384, FS=64, FM=16, FC=16 -> I=96; H=32.
//
// R13: ZERO global ops and ZERO barriers in the 24-step serial loop.
//  - 1024 blocks x 64 thr (1 wave). Wave owns 16 seqs x all 96 gate rows
//    (R10 all-in-register sigma recurrence, validated).
//  - Prologue: stage the wave's ENTIRE x history (24 steps x 16 seqs x
//    32 feats, f16) into 24 KB LDS via coalesced loads; gather weights
//    directly from W_ih/W_hh/b_*/Wp (R12-validated, RN-pack, log2e-scaled).
//  - Loop: 1 ds_read_b128 (own-wave LDS -> no barrier, HW-ordered) +
//    6 f16 MFMAs + merged-rcp gates (R11-validated). No VMEM anywhere.
//  - 4 blocks/CU (LDS 4x24KB=96 of 160 KB), all 1024 blocks resident.

typedef __attribute__((ext_vector_type(8))) _Float16 half8;
typedef __attribute__((ext_vector_type(4))) float f32x4;
typedef __attribute__((ext_vector_type(4))) unsigned int uix4;

#define NSEQ 16384
#define TSTEPS 24
#define LOG2E 1.44269504088896340736f

__device__ __forceinline__ float exp2_fast(float x) {
#if __has_builtin(__builtin_amdgcn_exp2f)
  return __builtin_amdgcn_exp2f(x);
#else
  return __expf(x * 0.6931471805599453f);
#endif
}

// runtime pack (RTZ) — data
__device__ __forceinline__ unsigned int pk_f16(float a, float b) {
#if __has_builtin(__builtin_amdgcn_cvt_pkrtz)
  auto r = __builtin_amdgcn_cvt_pkrtz(a, b);
  return __builtin_bit_cast(unsigned int, r);
#else
  return (unsigned)__half_as_ushort(__float2half(a)) |
         ((unsigned)__half_as_ushort(__float2half(b)) << 16);
#endif
}
// prologue pack (RN) — weights
__device__ __forceinline__ unsigned int pk_f16_rn(float a, float b) {
  return (unsigned)__half_as_ushort(__float2half(a)) |
         ((unsigned)__half_as_ushort(__float2half(b)) << 16);
}
__device__ __forceinline__ half8 mk_h8(unsigned int a, unsigned int b,
                                       unsigned int c, unsigned int d) {
  uix4 v = {a, b, c, d};
  return __builtin_bit_cast(half8, v);
}
__device__ __forceinline__ f32x4 mfma_h(half8 a, half8 b, f32x4 c) {
  return __builtin_amdgcn_mfma_f32_16x16x32_f16(a, b, c, 0, 0, 0);
}

__global__ __launch_bounds__(64, 1)
void gru9(const float* __restrict__ spatial,
          const float* __restrict__ met,
          const float* __restrict__ ctx,
          const float* __restrict__ W_ih,
          const float* __restrict__ W_hh,
          const float* __restrict__ b_ih,
          const float* __restrict__ b_hh,
          const float* __restrict__ Wp,
          float* __restrict__ out) {
  // full x history for this wave's 16 seqs: [t][seq][16 dwords = 32 f16]
  __shared__ unsigned int xst[TSTEPS][16][16];

  const int lane = threadIdx.x & 63;
  const int l15 = lane & 15;
  const int c = lane >> 4;         // 0..3
  const int seq = blockIdx.x * 16 + l15;
  const f32x4 zero4 = {0.f, 0.f, 0.f, 0.f};

  // ---- stage x history: lane stages its own seq at t = c, c+4, ..., c+20 ----
#pragma unroll
  for (int tt = 0; tt < 6; ++tt) {
    const int t = c + tt * 4;
    const float* mp = met + ((size_t)t * NSEQ + seq) * 16;
    const float* cp = ctx + ((size_t)t * NSEQ + seq) * 16;
    float4 m0 = *(const float4*)mp;       float4 m1 = *(const float4*)(mp + 4);
    float4 m2 = *(const float4*)(mp + 8); float4 m3 = *(const float4*)(mp + 12);
    float4 c0 = *(const float4*)cp;       float4 c1 = *(const float4*)(cp + 4);
    float4 c2 = *(const float4*)(cp + 8); float4 c3 = *(const float4*)(cp + 12);
    unsigned int* dst = &xst[t][l15][0];
    uix4 w0 = {pk_f16(m0.x, m0.y), pk_f16(m0.z, m0.w),
               pk_f16(m1.x, m1.y), pk_f16(m1.z, m1.w)};
    uix4 w1 = {pk_f16(m2.x, m2.y), pk_f16(m2.z, m2.w),
               pk_f16(m3.x, m3.y), pk_f16(m3.z, m3.w)};
    uix4 w2 = {pk_f16(c0.x, c0.y), pk_f16(c0.z, c0.w),
               pk_f16(c1.x, c1.y), pk_f16(c1.z, c1.w)};
    uix4 w3 = {pk_f16(c2.x, c2.y), pk_f16(c2.z, c2.w),
               pk_f16(c3.x, c3.y), pk_f16(c3.z, c3.w)};
    *(uix4*)&dst[0]  = w0;  *(uix4*)&dst[4]  = w1;
    *(uix4*)&dst[8]  = w2;  *(uix4*)&dst[12] = w3;
  }

  // ---- weights: direct gather (sigma cols for W_hh), RN pack, scaled ----
  half8 whh[6], wmc[6];
  f32x4 acc_i[6], bhnA, bhnB;
#pragma unroll
  for (int j = 0; j < 6; ++j) {
    const float sc = (j < 4) ? LOG2E : (2.0f * LOG2E);
    const float* wr = W_hh + (size_t)(j * 16 + l15) * 32;
    float4 a = *(const float4*)(wr + 4 * c);
    float4 b = *(const float4*)(wr + 16 + 4 * c);
    whh[j] = mk_h8(pk_f16_rn(a.x * sc, a.y * sc), pk_f16_rn(a.z * sc, a.w * sc),
                   pk_f16_rn(b.x * sc, b.y * sc), pk_f16_rn(b.z * sc, b.w * sc));
    const float* mr = W_ih + (size_t)(j * 16 + l15) * 96 + 64 + c * 8;
    float4 wa = *(const float4*)mr;
    float4 wb = *(const float4*)(mr + 4);
    wmc[j] = mk_h8(pk_f16_rn(wa.x * sc, wa.y * sc), pk_f16_rn(wa.z * sc, wa.w * sc),
                   pk_f16_rn(wb.x * sc, wb.y * sc), pk_f16_rn(wb.z * sc, wb.w * sc));
    // bias for rows j*16 + 4c + q
    const int rowb = j * 16 + 4 * c;
    float4 vih = *(const float4*)(b_ih + rowb);
    if (j < 4) {
      float4 vhh = *(const float4*)(b_hh + rowb);
      acc_i[j][0] = (vih.x + vhh.x) * sc; acc_i[j][1] = (vih.y + vhh.y) * sc;
      acc_i[j][2] = (vih.z + vhh.z) * sc; acc_i[j][3] = (vih.w + vhh.w) * sc;
    } else {
      acc_i[j][0] = vih.x * sc; acc_i[j][1] = vih.y * sc;
      acc_i[j][2] = vih.z * sc; acc_i[j][3] = vih.w * sc;
    }
  }
  {
    float4 va = *(const float4*)(b_hh + 64 + 4 * c);
    float4 vb = *(const float4*)(b_hh + 64 + 16 + 4 * c);
    bhnA[0] = 2.0f * LOG2E * va.x; bhnA[1] = 2.0f * LOG2E * va.y;
    bhnA[2] = 2.0f * LOG2E * va.z; bhnA[3] = 2.0f * LOG2E * va.w;
    bhnB[0] = 2.0f * LOG2E * vb.x; bhnB[1] = 2.0f * LOG2E * vb.y;
    bhnB[2] = 2.0f * LOG2E * vb.z; bhnB[3] = 2.0f * LOG2E * vb.w;
  }

  // ---- fold spatial (time-invariant) into acc_i ----
#pragma unroll
  for (int kt = 0; kt < 2; ++kt) {
    const float* sp = spatial + (size_t)seq * 64 + kt * 32 + c * 8;
    float4 a0 = *(const float4*)sp;
    float4 a1 = *(const float4*)(sp + 4);
    half8 sf = mk_h8(pk_f16(a0.x, a0.y), pk_f16(a0.z, a0.w),
                     pk_f16(a1.x, a1.y), pk_f16(a1.z, a1.w));
#pragma unroll
    for (int j = 0; j < 6; ++j) {
      const float sc = (j < 4) ? LOG2E : (2.0f * LOG2E);
      const float* wr = W_ih + (size_t)(j * 16 + l15) * 96 + kt * 32 + c * 8;
      float4 wa = *(const float4*)wr;
      float4 wb = *(const float4*)(wr + 4);
      half8 wsp = mk_h8(pk_f16_rn(wa.x * sc, wa.y * sc),
                        pk_f16_rn(wa.z * sc, wa.w * sc),
                        pk_f16_rn(wb.x * sc, wb.y * sc),
                        pk_f16_rn(wb.z * sc, wb.w * sc));
      acc_i[j] = mfma_h(wsp, sf, acc_i[j]);
    }
  }

  // ---- xacc(0) from LDS x(0); prefetch x(1) ----
  f32x4 xacc[6];
  {
    uix4 v = *(const uix4*)&xst[0][l15][c * 4];
    half8 xf = __builtin_bit_cast(half8, v);
#pragma unroll
    for (int j = 0; j < 6; ++j) xacc[j] = mfma_h(wmc[j], xf, acc_i[j]);
  }
  half8 xf1;
  {
    uix4 v = *(const uix4*)&xst[1][l15][c * 4];
    xf1 = __builtin_bit_cast(half8, v);
  }

  float hst[8];
#pragma unroll
  for (int i = 0; i < 8; ++i) hst[i] = 0.0f;
  half8 fh = mk_h8(0u, 0u, 0u, 0u);

  // ---- serial recurrence: NO global memory, NO barriers ----
#pragma unroll 4
  for (int t = 0; t < TSTEPS; ++t) {
    // h-side (6 independent MFMAs; C = precomputed input parts)
    f32x4 dr0 = mfma_h(whh[0], fh, xacc[0]);
    f32x4 dr1 = mfma_h(whh[1], fh, xacc[1]);
    f32x4 dz0 = mfma_h(whh[2], fh, xacc[2]);
    f32x4 dz1 = mfma_h(whh[3], fh, xacc[3]);
    f32x4 th0 = mfma_h(whh[4], fh, bhnA);
    f32x4 th1 = mfma_h(whh[5], fh, bhnB);
    f32x4 ti0 = xacc[4], ti1 = xacc[5];   // save n-gate input parts

    // x-side for t+1 (h-independent), then prefetch x(t+2) from LDS
#pragma unroll
    for (int j = 0; j < 6; ++j) xacc[j] = mfma_h(wmc[j], xf1, acc_i[j]);
    if (t + 2 < TSTEPS) {
      uix4 v = *(const uix4*)&xst[t + 2][l15][c * 4];
      xf1 = __builtin_bit_cast(half8, v);
    }

    // merged-rcp gates: h' = [h(1+e) + E(1-e)] / [(1+E)(1+e)]
    float hv_[8];
#pragma unroll
    for (int jj = 0; jj < 2; ++jj) {
      f32x4 ddr = jj ? dr1 : dr0;
      f32x4 ddz = jj ? dz1 : dz0;
      f32x4 tth = jj ? th1 : th0;
      f32x4 tti = jj ? ti1 : ti0;
#pragma unroll
      for (int q = 0; q < 4; ++q) {
        const int i = jj * 4 + q;
        float R = exp2_fast(-ddr[q]);
        float r = __builtin_amdgcn_rcpf(1.0f + R);
        float E = fminf(exp2_fast(-ddz[q]), 1e30f);
        float Y = fmaf(r, tth[q], tti[q]);
        float e = fminf(exp2_fast(-Y), 1e30f);
        float oe = 1.0f + e, oE = 1.0f + E;
        float inv = __builtin_amdgcn_rcpf(oE * oe);
        float num = fmaf(hst[i], oe, fmaf(-E, e, E));
        float hv = num * inv;
        hst[i] = hv;
        hv_[i] = hv;
      }
    }
    fh = mk_h8(pk_f16(hv_[0], hv_[1]), pk_f16(hv_[2], hv_[3]),
               pk_f16(hv_[4], hv_[5]), pk_f16(hv_[6], hv_[7]));
  }

  // ---- projection: all 4 f-tiles; Wp gathered (sigma cols), f16 2-term ----
#pragma unroll
  for (int pt = 0; pt < 4; ++pt) {
    const int frow = pt * 16 + l15;
    const float* wpb = Wp + frow;
    float v[8];
#pragma unroll
    for (int e = 0; e < 8; ++e) {
      int col = (e < 4) ? (4 * c + e) : (16 + 4 * c + (e - 4));
      v[e] = wpb[(size_t)col * 64];
    }
    unsigned int uh[4], ul[4];
#pragma unroll
    for (int e2 = 0; e2 < 4; ++e2) {
      float va = v[2 * e2], vb = v[2 * e2 + 1];
      __half ha = __float2half(va), hb = __float2half(vb);
      float la = va - __half2float(ha), lb = vb - __half2float(hb);
      uh[e2] = (unsigned)__half_as_ushort(ha) |
               ((unsigned)__half_as_ushort(hb) << 16);
      ul[e2] = pk_f16_rn(la, lb);
    }
    half8 wph = mk_h8(uh[0], uh[1], uh[2], uh[3]);
    half8 wpl = mk_h8(ul[0], ul[1], ul[2], ul[3]);
    f32x4 o = mfma_h(wph, fh, zero4);
    o = mfma_h(wpl, fh, o);
    float* op = out + (size_t)seq * 64 + pt * 16 + 4 * c;
    *(float4*)op = make_float4(o[0], o[1], o[2], o[3]);
  }
}

extern "C" void kernel_launch(void* const* d_in, const int* in_sizes, int n_in,
                              void* d_out, int out_size, void* d_ws, size_t ws_size,
                              hipStream_t stream) {
  const float* spatial = (const float*)d_in[0];
  const float* met     = (const float*)d_in[1];
  const float* ctx     = (const float*)d_in[2];
  const float* W_ih    = (const float*)d_in[3];
  const float* W_hh    = (const float*)d_in[4];
  const float* b_ih    = (const float*)d_in[5];
  const float* b_hh    = (const float*)d_in[6];
  const float* Wp      = (const float*)d_in[7];
  float* out = (float*)d_out;

  hipLaunchKernelGGL(gru9, dim3(1024), dim3(64), 0, stream,
                     spatial, met, ctx, W_ih, W_hh, b_ih, b_hh, Wp, out);
}

// Round 14
// 23.506 us; speedup vs baseline: 1.2925x; 1.2925x over previous
//
#include <hip/hip_runtime.h>
#include <hip/hip_fp16.h>
#include <math.h>

// T=24, NSEQ=16384, FS=64, FM=16, FC=16 -> I=96; H=32.
//
// R14: pair-based producer/consumer with IN-REGISTER h recurrence.
//  - block = 128 thr: wave0 = CONSUMER (all 32 units, R10 sigma-layout
//    recurrence -> h' never leaves registers, no h-exchange, no partner),
//    wave1 = PRODUCER (all 6 xacc tiles: bias+spatial+Wmc*x(t+1) ->
//    double-buffered LDS, R12 mechanics).
//  - 1024 blocks = 2048 waves = 2/SIMD; 8 blocks/CU; barrier couples
//    only 2 waves (minimal skew). One lgkm-only barrier/step.
//  - Serial path/step: 6 ds_read_b128 -> 6 independent f16 MFMAs ->
//    merged-rcp gates (5 trans/unit, algebraic minimum) -> pack.
//  - Weights gathered directly (R12-validated), RN-pack, log2e-scaled.

typedef __attribute__((ext_vector_type(8))) _Float16 half8;
typedef __attribute__((ext_vector_type(4))) float f32x4;
typedef __attribute__((ext_vector_type(4))) unsigned int uix4;

#define NSEQ 16384
#define TSTEPS 24
#define LOG2E 1.44269504088896340736f

__device__ __forceinline__ float exp2_fast(float x) {
#if __has_builtin(__builtin_amdgcn_exp2f)
  return __builtin_amdgcn_exp2f(x);
#else
  return __expf(x * 0.6931471805599453f);
#endif
}

// runtime pack (RTZ) — data
__device__ __forceinline__ unsigned int pk_f16(float a, float b) {
#if __has_builtin(__builtin_amdgcn_cvt_pkrtz)
  auto r = __builtin_amdgcn_cvt_pkrtz(a, b);
  return __builtin_bit_cast(unsigned int, r);
#else
  return (unsigned)__half_as_ushort(__float2half(a)) |
         ((unsigned)__half_as_ushort(__float2half(b)) << 16);
#endif
}
// prologue pack (RN) — weights
__device__ __forceinline__ unsigned int pk_f16_rn(float a, float b) {
  return (unsigned)__half_as_ushort(__float2half(a)) |
         ((unsigned)__half_as_ushort(__float2half(b)) << 16);
}
__device__ __forceinline__ half8 mk_h8(unsigned int a, unsigned int b,
                                       unsigned int c, unsigned int d) {
  uix4 v = {a, b, c, d};
  return __builtin_bit_cast(half8, v);
}
__device__ __forceinline__ f32x4 mfma_h(half8 a, half8 b, f32x4 c) {
  return __builtin_amdgcn_mfma_f32_16x16x32_f16(a, b, c, 0, 0, 0);
}

// workgroup barrier draining LDS ops only
__device__ __forceinline__ void barrier_lds() {
  asm volatile("s_waitcnt lgkmcnt(0)" ::: "memory");
  __builtin_amdgcn_s_barrier();
}

__global__ __launch_bounds__(128, 4)
void gru10(const float* __restrict__ spatial,
           const float* __restrict__ met,
           const float* __restrict__ ctx,
           const float* __restrict__ W_ih,
           const float* __restrict__ W_hh,
           const float* __restrict__ b_ih,
           const float* __restrict__ b_hh,
           const float* __restrict__ Wp,
           float* __restrict__ out) {
  // xacc tiles: [buf][tile j=0..5][seq 16][20-pad f32]  (15.4 KB)
  __shared__ float xls[2][6][16][20];

  const int tid = threadIdx.x;
  const int lane = tid & 63;
  const int wv = tid >> 6;         // 0 = consumer, 1 = producer
  const int l15 = lane & 15;
  const int c = lane >> 4;         // 0..3
  const int seq = blockIdx.x * 16 + l15;
  const f32x4 zero4 = {0.f, 0.f, 0.f, 0.f};

  if (wv == 1) {
    // ======================= PRODUCER (all 6 tiles) =======================
    half8 wmc[6];
    f32x4 acc_i[6];
#pragma unroll
    for (int j = 0; j < 6; ++j) {
      const float sc = (j < 4) ? LOG2E : (2.0f * LOG2E);
      const float* mr = W_ih + (size_t)(j * 16 + l15) * 96 + 64 + c * 8;
      float4 wa = *(const float4*)mr;
      float4 wb = *(const float4*)(mr + 4);
      wmc[j] = mk_h8(pk_f16_rn(wa.x * sc, wa.y * sc),
                     pk_f16_rn(wa.z * sc, wa.w * sc),
                     pk_f16_rn(wb.x * sc, wb.y * sc),
                     pk_f16_rn(wb.z * sc, wb.w * sc));
      const int rowb = j * 16 + 4 * c;
      float4 vih = *(const float4*)(b_ih + rowb);
      if (j < 4) {
        float4 vhh = *(const float4*)(b_hh + rowb);
        acc_i[j][0] = (vih.x + vhh.x) * sc; acc_i[j][1] = (vih.y + vhh.y) * sc;
        acc_i[j][2] = (vih.z + vhh.z) * sc; acc_i[j][3] = (vih.w + vhh.w) * sc;
      } else {
        acc_i[j][0] = vih.x * sc; acc_i[j][1] = vih.y * sc;
        acc_i[j][2] = vih.z * sc; acc_i[j][3] = vih.w * sc;
      }
    }
    // fold spatial (time-invariant)
#pragma unroll
    for (int kt = 0; kt < 2; ++kt) {
      const float* sp = spatial + (size_t)seq * 64 + kt * 32 + c * 8;
      float4 a0 = *(const float4*)sp;
      float4 a1 = *(const float4*)(sp + 4);
      half8 sf = mk_h8(pk_f16(a0.x, a0.y), pk_f16(a0.z, a0.w),
                       pk_f16(a1.x, a1.y), pk_f16(a1.z, a1.w));
#pragma unroll
      for (int j = 0; j < 6; ++j) {
        const float sc = (j < 4) ? LOG2E : (2.0f * LOG2E);
        const float* wr = W_ih + (size_t)(j * 16 + l15) * 96 + kt * 32 + c * 8;
        float4 wa = *(const float4*)wr;
        float4 wb = *(const float4*)(wr + 4);
        half8 wsp = mk_h8(pk_f16_rn(wa.x * sc, wa.y * sc),
                          pk_f16_rn(wa.z * sc, wa.w * sc),
                          pk_f16_rn(wb.x * sc, wb.y * sc),
                          pk_f16_rn(wb.z * sc, wb.w * sc));
        acc_i[j] = mfma_h(wsp, sf, acc_i[j]);
      }
    }
    const float* lptr = ((c < 2) ? met : ctx) + (size_t)seq * 16 + (c & 1) * 8;
    // xacc(0) -> buffer 0
    {
      float4 a0 = *(const float4*)lptr;
      float4 a1 = *(const float4*)(lptr + 4);
      half8 xf = mk_h8(pk_f16(a0.x, a0.y), pk_f16(a0.z, a0.w),
                       pk_f16(a1.x, a1.y), pk_f16(a1.z, a1.w));
#pragma unroll
      for (int j = 0; j < 6; ++j) {
        f32x4 D = mfma_h(wmc[j], xf, acc_i[j]);
        *(f32x4*)&xls[0][j][l15][c * 4] = D;
      }
    }
    // parity slots: slot s holds x(t+1) for step t with t&1==s
    float4 xs0a = *(const float4*)(lptr + (size_t)1 * NSEQ * 16);
    float4 xs0b = *(const float4*)(lptr + (size_t)1 * NSEQ * 16 + 4);
    float4 xs1a = *(const float4*)(lptr + (size_t)2 * NSEQ * 16);
    float4 xs1b = *(const float4*)(lptr + (size_t)2 * NSEQ * 16 + 4);

    barrier_lds();

#pragma unroll 2
    for (int t = 0; t < TSTEPS; ++t) {
      float4 xa = (t & 1) ? xs1a : xs0a;
      float4 xb = (t & 1) ? xs1b : xs0b;
      half8 xf = mk_h8(pk_f16(xa.x, xa.y), pk_f16(xa.z, xa.w),
                       pk_f16(xb.x, xb.y), pk_f16(xb.z, xb.w));
      // refill slot with x(t+3) (used at step t+2)
      {
        int tf = (t + 3 < TSTEPS) ? (t + 3) : (TSTEPS - 1);
        float4 na = *(const float4*)(lptr + (size_t)tf * NSEQ * 16);
        float4 nb = *(const float4*)(lptr + (size_t)tf * NSEQ * 16 + 4);
        if (t & 1) { xs1a = na; xs1b = nb; } else { xs0a = na; xs0b = nb; }
      }
      const int buf = (t + 1) & 1;
#pragma unroll
      for (int j = 0; j < 6; ++j) {
        f32x4 D = mfma_h(wmc[j], xf, acc_i[j]);
        *(f32x4*)&xls[buf][j][l15][c * 4] = D;
      }
      barrier_lds();
    }
    // producer done
  } else {
    // ======================= CONSUMER (all 32 units) =======================
    __builtin_amdgcn_s_setprio(1);
    half8 whh[6];
#pragma unroll
    for (int j = 0; j < 6; ++j) {
      const float sc = (j < 4) ? LOG2E : (2.0f * LOG2E);
      const float* wr = W_hh + (size_t)(j * 16 + l15) * 32;
      float4 a = *(const float4*)(wr + 4 * c);
      float4 b = *(const float4*)(wr + 16 + 4 * c);
      whh[j] = mk_h8(pk_f16_rn(a.x * sc, a.y * sc),
                     pk_f16_rn(a.z * sc, a.w * sc),
                     pk_f16_rn(b.x * sc, b.y * sc),
                     pk_f16_rn(b.z * sc, b.w * sc));
    }
    f32x4 bhnA, bhnB;
    {
      float4 va = *(const float4*)(b_hh + 64 + 4 * c);
      float4 vb = *(const float4*)(b_hh + 64 + 16 + 4 * c);
      bhnA[0] = 2.0f * LOG2E * va.x; bhnA[1] = 2.0f * LOG2E * va.y;
      bhnA[2] = 2.0f * LOG2E * va.z; bhnA[3] = 2.0f * LOG2E * va.w;
      bhnB[0] = 2.0f * LOG2E * vb.x; bhnB[1] = 2.0f * LOG2E * vb.y;
      bhnB[2] = 2.0f * LOG2E * vb.z; bhnB[3] = 2.0f * LOG2E * vb.w;
    }
    float hst[8];
#pragma unroll
    for (int i = 0; i < 8; ++i) hst[i] = 0.0f;
    half8 fh = mk_h8(0u, 0u, 0u, 0u);

    barrier_lds();

#pragma unroll 2
    for (int t = 0; t < TSTEPS; ++t) {
      const int buf = t & 1;
      // all 6 xacc C-tiles (ds_read_b128 x6, issued together)
      f32x4 xr0 = *(const f32x4*)&xls[buf][0][l15][c * 4];
      f32x4 xr1 = *(const f32x4*)&xls[buf][1][l15][c * 4];
      f32x4 xz0 = *(const f32x4*)&xls[buf][2][l15][c * 4];
      f32x4 xz1 = *(const f32x4*)&xls[buf][3][l15][c * 4];
      f32x4 ti0 = *(const f32x4*)&xls[buf][4][l15][c * 4];
      f32x4 ti1 = *(const f32x4*)&xls[buf][5][l15][c * 4];

      // 6 independent h-MFMAs (R10 structure, h' in-register via sigma)
      f32x4 dr0 = mfma_h(whh[0], fh, xr0);
      f32x4 dr1 = mfma_h(whh[1], fh, xr1);
      f32x4 dz0 = mfma_h(whh[2], fh, xz0);
      f32x4 dz1 = mfma_h(whh[3], fh, xz1);
      f32x4 th0 = mfma_h(whh[4], fh, bhnA);
      f32x4 th1 = mfma_h(whh[5], fh, bhnB);

      // merged-rcp gates: h' = [h(1+e) + E(1-e)] / [(1+E)(1+e)]
      float hv_[8];
#pragma unroll
      for (int jj = 0; jj < 2; ++jj) {
        f32x4 ddr = jj ? dr1 : dr0;
        f32x4 ddz = jj ? dz1 : dz0;
        f32x4 tth = jj ? th1 : th0;
        f32x4 tti = jj ? ti1 : ti0;
#pragma unroll
        for (int q = 0; q < 4; ++q) {
          const int i = jj * 4 + q;
          float R = exp2_fast(-ddr[q]);
          float r = __builtin_amdgcn_rcpf(1.0f + R);
          float E = fminf(exp2_fast(-ddz[q]), 1e30f);
          float Y = fmaf(r, tth[q], tti[q]);
          float e = fminf(exp2_fast(-Y), 1e30f);
          float oe = 1.0f + e, oE = 1.0f + E;
          float inv = __builtin_amdgcn_rcpf(oE * oe);
          float num = fmaf(hst[i], oe, fmaf(-E, e, E));
          float hv = num * inv;
          hst[i] = hv;
          hv_[i] = hv;
        }
      }
      fh = mk_h8(pk_f16(hv_[0], hv_[1]), pk_f16(hv_[2], hv_[3]),
                 pk_f16(hv_[4], hv_[5]), pk_f16(hv_[6], hv_[7]));

      barrier_lds();
    }

    // ---- projection: all 4 f-tiles; Wp gathered (sigma cols), f16 2-term ----
#pragma unroll
    for (int pt = 0; pt < 4; ++pt) {
      const int frow = pt * 16 + l15;
      const float* wpb = Wp + frow;
      float v[8];
#pragma unroll
      for (int e = 0; e < 8; ++e) {
        int col = (e < 4) ? (4 * c + e) : (16 + 4 * c + (e - 4));
        v[e] = wpb[(size_t)col * 64];
      }
      unsigned int uh[4], ul[4];
#pragma unroll
      for (int e2 = 0; e2 < 4; ++e2) {
        float va = v[2 * e2], vb = v[2 * e2 + 1];
        __half ha = __float2half(va), hb = __float2half(vb);
        float la = va - __half2float(ha), lb = vb - __half2float(hb);
        uh[e2] = (unsigned)__half_as_ushort(ha) |
                 ((unsigned)__half_as_ushort(hb) << 16);
        ul[e2] = pk_f16_rn(la, lb);
      }
      half8 wph = mk_h8(uh[0], uh[1], uh[2], uh[3]);
      half8 wpl = mk_h8(ul[0], ul[1], ul[2], ul[3]);
      f32x4 o = mfma_h(wph, fh, zero4);
      o = mfma_h(wpl, fh, o);
      float* op = out + (size_t)seq * 64 + pt * 16 + 4 * c;
      *(float4*)op = make_float4(o[0], o[1], o[2], o[3]);
    }
    __builtin_amdgcn_s_setprio(0);
  }
}

extern "C" void kernel_launch(void* const* d_in, const int* in_sizes, int n_in,
                              void* d_out, int out_size, void* d_ws, size_t ws_size,
                              hipStream_t stream) {
  const float* spatial = (const float*)d_in[0];
  const float* met     = (const float*)d_in[1];
  const float* ctx     = (const float*)d_in[2];
  const float* W_ih    = (const float*)d_in[3];
  const float* W_hh    = (const float*)d_in[4];
  const float* b_ih    = (const float*)d_in[5];
  const float* b_hh    = (const float*)d_in[6];
  const float* Wp      = (const float*)d_in[7];
  float* out = (float*)d_out;

  hipLaunchKernelGGL(gru10, dim3(1024), dim3(128), 0, stream,
                     spatial, met, ctx, W_ih, W_hh, b_ih, b_hh, Wp, out);
}